// Round 4
// baseline (1827.938 us; speedup 1.0000x reference)
//
#include <hip/hip_runtime.h>

#define NB 16
#define NPTS 4096
#define NC 64
#define NS 1024
#define NK 32

// ---------------------------------------------------------------------------
// FPS: one block per batch, 1024 threads, 4 points per thread in registers.
// fp32 direct-form distances (verified: output 0 exact).
// ---------------------------------------------------------------------------
__global__ __launch_bounds__(1024) void fps_kernel(const float* __restrict__ xyz,
                                                   float* __restrict__ out_xyz) {
    __shared__ float sx[NPTS], sy[NPTS], sz[NPTS];
    __shared__ float rd[2][16];
    __shared__ int   ri[2][16];

    const int b = blockIdx.x;
    const int t = threadIdx.x;
    const int lane = t & 63;

    const float* xb = xyz + (size_t)b * NPTS * 3;
    for (int i = t; i < NPTS; i += 1024) {
        sx[i] = xb[3 * i];
        sy[i] = xb[3 * i + 1];
        sz[i] = xb[3 * i + 2];
    }
    __syncthreads();

    float px[4], py[4], pz[4], dm[4];
#pragma unroll
    for (int j = 0; j < 4; ++j) {
        const int p = t + j * 1024;
        px[j] = sx[p]; py[j] = sy[p]; pz[j] = sz[p];
        dm[j] = 1e10f;
    }

    float cx = sx[0], cy = sy[0], cz = sz[0];
    float* ob = out_xyz + (size_t)b * NS * 3;
    const int wv = t >> 6;

    for (int s = 0; s < NS; ++s) {
        if (t == 0) { ob[3 * s] = cx; ob[3 * s + 1] = cy; ob[3 * s + 2] = cz; }

        float bd = -1.0f;
        int bi = 0;
#pragma unroll
        for (int j = 0; j < 4; ++j) {
            const float dx = __fsub_rn(px[j], cx);
            const float dy = __fsub_rn(py[j], cy);
            const float dz = __fsub_rn(pz[j], cz);
            const float d = __fadd_rn(__fadd_rn(__fmul_rn(dx, dx), __fmul_rn(dy, dy)),
                                      __fmul_rn(dz, dz));
            dm[j] = fminf(dm[j], d);
            if (dm[j] > bd) { bd = dm[j]; bi = t + j * 1024; }
        }
        // wave argmax (value desc, index asc on ties)
#pragma unroll
        for (int m = 1; m < 64; m <<= 1) {
            const float od = __shfl_xor(bd, m);
            const int   oi = __shfl_xor(bi, m);
            if (od > bd || (od == bd && oi < bi)) { bd = od; bi = oi; }
        }
        if (lane == 0) { rd[s & 1][wv] = bd; ri[s & 1][wv] = bi; }
        __syncthreads();
        float vd = (lane < 16) ? rd[s & 1][lane] : -1.0f;
        int   vi = (lane < 16) ? ri[s & 1][lane] : 0x7fffffff;
#pragma unroll
        for (int m = 1; m < 16; m <<= 1) {
            const float od = __shfl_xor(vd, m);
            const int   oi = __shfl_xor(vi, m);
            if (od > vd || (od == vd && oi < vi)) { vd = od; vi = oi; }
        }
        const int wi = __shfl(vi, 0);
        cx = sx[wi]; cy = sy[wi]; cz = sz[wi];
    }
}

// ---------------------------------------------------------------------------
// KNN: one wave per query. fp32 expanded-form distances replicating the
// reference's rounding: dot as an FMA chain (numpy SIMD / BLAS style),
// d = (qsq - 2*dot) + psq left-to-right, qsq/psq sequential no-FMA.
// Per-lane sorted top-4 + lazy refill; 32 rounds of wave argmin.
// ---------------------------------------------------------------------------
#define KNN_INF 3.0e38f

__global__ __launch_bounds__(1024) void knn_kernel(const float* __restrict__ xyz,
                                                   const float* __restrict__ newxyz,
                                                   unsigned short* __restrict__ knn) {
    __shared__ float4 pts[NPTS];

    const int b = blockIdx.x >> 6;
    const int t = threadIdx.x;
    const float* xb = xyz + (size_t)b * NPTS * 3;
    for (int i = t; i < NPTS; i += 1024) {
        const float x = xb[3 * i], y = xb[3 * i + 1], z = xb[3 * i + 2];
        const float ps = __fadd_rn(__fadd_rn(__fmul_rn(x, x), __fmul_rn(y, y)), __fmul_rn(z, z));
        pts[i] = make_float4(x, y, z, ps);
    }
    __syncthreads();

    const int lane = t & 63;
    const int wv = t >> 6;
    const int s = ((blockIdx.x & 63) << 4) + wv;

    const float* q = newxyz + ((size_t)b * NS + s) * 3;
    const float qx = q[0], qy = q[1], qz = q[2];
    const float qs = __fadd_rn(__fadd_rn(__fmul_rn(qx, qx), __fmul_rn(qy, qy)), __fmul_rn(qz, qz));

    float v0 = KNN_INF, v1 = KNN_INF, v2 = KNN_INF, v3 = KNN_INF;
    int i0 = 0, i1 = 0, i2 = 0, i3 = 0;
    unsigned long long rem = 0ull;

#pragma unroll 4
    for (int j = 0; j < 64; ++j) {
        const float4 p = pts[j * 64 + lane];
        const float dot = __fmaf_rn(qz, p.z, __fmaf_rn(qy, p.y, __fmul_rn(qx, p.x)));
        const float d = __fadd_rn(__fsub_rn(qs, __fadd_rn(dot, dot)), p.w);
        const int gi = j * 64 + lane;
        const bool c0 = d < v0, c1 = d < v1, c2 = d < v2, c3 = d < v3;
        v3 = c3 ? (c2 ? v2 : d) : v3;  i3 = c3 ? (c2 ? i2 : gi) : i3;
        v2 = c2 ? (c1 ? v1 : d) : v2;  i2 = c2 ? (c1 ? i1 : gi) : i2;
        v1 = c1 ? (c0 ? v0 : d) : v1;  i1 = c1 ? (c0 ? i0 : gi) : i1;
        v0 = c0 ? d : v0;              i0 = c0 ? gi : i0;
    }

    int kidx = 0;
#pragma unroll 1
    for (int r = 0; r < NK; ++r) {
        float bv = v0;
        int bi = i0;
#pragma unroll
        for (int m = 1; m < 64; m <<= 1) {
            const float ov = __shfl_xor(bv, m);
            const int   oi = __shfl_xor(bi, m);
            if (ov < bv || (ov == bv && oi < bi)) { bv = ov; bi = oi; }
        }
        if (lane == r) kidx = bi;
        if ((bi & 63) == lane) {
            // pop my head
            v0 = v1; i0 = i1;
            v1 = v2; i1 = i2;
            v2 = v3; i2 = i3;
            v3 = KNN_INF;
            rem |= 1ull << (bi >> 6);
            if (v0 >= 1e37f) {
                // refill from LDS, excluding already-popped slots
                v0 = v1 = v2 = v3 = KNN_INF;
#pragma unroll 1
                for (int j = 0; j < 64; ++j) {
                    if (!((rem >> j) & 1ull)) {
                        const float4 p = pts[j * 64 + lane];
                        const float dot = __fmaf_rn(qz, p.z, __fmaf_rn(qy, p.y, __fmul_rn(qx, p.x)));
                        const float d = __fadd_rn(__fsub_rn(qs, __fadd_rn(dot, dot)), p.w);
                        const int gi = j * 64 + lane;
                        const bool c0 = d < v0, c1 = d < v1, c2 = d < v2, c3 = d < v3;
                        v3 = c3 ? (c2 ? v2 : d) : v3;  i3 = c3 ? (c2 ? i2 : gi) : i3;
                        v2 = c2 ? (c1 ? v1 : d) : v2;  i2 = c2 ? (c1 ? i1 : gi) : i2;
                        v1 = c1 ? (c0 ? v0 : d) : v1;  i1 = c1 ? (c0 ? i0 : gi) : i1;
                        v0 = c0 ? d : v0;              i0 = c0 ? gi : i0;
                    }
                }
            }
        }
    }

    if (lane < NK) knn[(((size_t)b * NS + s) << 5) + lane] = (unsigned short)kidx;
}

// ---------------------------------------------------------------------------
// Gather + 3-layer 1x1-conv MLP + max-pool over K.
// One lane per (group, neighbor) row; 2 groups per wave; 8 groups per block.
// ---------------------------------------------------------------------------
__global__ __launch_bounds__(256) void mlp_kernel(const float* __restrict__ xyz,
                                                  const float* __restrict__ points,
                                                  const float* __restrict__ newxyz,
                                                  const unsigned short* __restrict__ knn,
                                                  const float* __restrict__ w0, const float* __restrict__ b0,
                                                  const float* __restrict__ w1, const float* __restrict__ b1,
                                                  const float* __restrict__ w2, const float* __restrict__ b2,
                                                  float* __restrict__ out) {
    __shared__ float act[67][256];

    const int t = threadIdx.x;
    const int lane = t & 63;
    const int g = blockIdx.x * 8 + ((t >> 6) << 1) + ((lane >> 5) & 1);
    const int b = g >> 10;
    const int k = lane & 31;

    const int idx = knn[((size_t)g << 5) + k];
    const float* nq = newxyz + (size_t)g * 3;
    const float* pp = xyz + ((size_t)b * NPTS + idx) * 3;
    act[0][t] = pp[0] - nq[0];
    act[1][t] = pp[1] - nq[1];
    act[2][t] = pp[2] - nq[2];
    const float4* pr = (const float4*)(points + (((size_t)b * NPTS + idx) << 6));
#pragma unroll
    for (int j = 0; j < 16; ++j) {
        const float4 v = pr[j];
        act[3 + 4 * j][t] = v.x;
        act[4 + 4 * j][t] = v.y;
        act[5 + 4 * j][t] = v.z;
        act[6 + 4 * j][t] = v.w;
    }

    float h[128];

    // layer 1: 67 -> 64
#pragma unroll
    for (int f = 0; f < 64; ++f) h[f] = b0[f];
#pragma unroll 1
    for (int i = 0; i < 67; ++i) {
        const float xi = act[i][t];
        const float* wr = w0 + (i << 6);
#pragma unroll
        for (int f = 0; f < 64; ++f) h[f] = fmaf(xi, wr[f], h[f]);
    }
#pragma unroll
    for (int f = 0; f < 64; ++f) act[f][t] = fmaxf(h[f], 0.0f);

    // layer 2: 64 -> 64
#pragma unroll
    for (int f = 0; f < 64; ++f) h[f] = b1[f];
#pragma unroll 1
    for (int i = 0; i < 64; ++i) {
        const float xi = act[i][t];
        const float* wr = w1 + (i << 6);
#pragma unroll
        for (int f = 0; f < 64; ++f) h[f] = fmaf(xi, wr[f], h[f]);
    }
#pragma unroll
    for (int f = 0; f < 64; ++f) act[f][t] = fmaxf(h[f], 0.0f);

    // layer 3: 64 -> 128
#pragma unroll
    for (int f = 0; f < 128; ++f) h[f] = b2[f];
#pragma unroll 1
    for (int i = 0; i < 64; ++i) {
        const float xi = act[i][t];
        const float* wr = w2 + (i << 7);
#pragma unroll
        for (int f = 0; f < 128; ++f) h[f] = fmaf(xi, wr[f], h[f]);
    }
#pragma unroll
    for (int f = 0; f < 128; ++f) h[f] = fmaxf(h[f], 0.0f);

    // butterfly reduce-scatter max over the 32 lanes of each half-wave.
    // final: lane owns channels 4*(lane&31) + e.
    float t64[64];
#pragma unroll
    for (int c = 0; c < 64; ++c) {
        const bool hi = (lane & 16);
        const float kept = hi ? h[c + 64] : h[c];
        const float snt  = hi ? h[c] : h[c + 64];
        t64[c] = fmaxf(kept, __shfl_xor(snt, 16));
    }
    float t32a[32];
#pragma unroll
    for (int c = 0; c < 32; ++c) {
        const bool hi = (lane & 8);
        const float kept = hi ? t64[c + 32] : t64[c];
        const float snt  = hi ? t64[c] : t64[c + 32];
        t32a[c] = fmaxf(kept, __shfl_xor(snt, 8));
    }
    float t16a[16];
#pragma unroll
    for (int c = 0; c < 16; ++c) {
        const bool hi = (lane & 4);
        const float kept = hi ? t32a[c + 16] : t32a[c];
        const float snt  = hi ? t32a[c] : t32a[c + 16];
        t16a[c] = fmaxf(kept, __shfl_xor(snt, 4));
    }
    float t8a[8];
#pragma unroll
    for (int c = 0; c < 8; ++c) {
        const bool hi = (lane & 2);
        const float kept = hi ? t16a[c + 8] : t16a[c];
        const float snt  = hi ? t16a[c] : t16a[c + 8];
        t8a[c] = fmaxf(kept, __shfl_xor(snt, 2));
    }
    float t4a[4];
#pragma unroll
    for (int c = 0; c < 4; ++c) {
        const bool hi = (lane & 1);
        const float kept = hi ? t8a[c + 4] : t8a[c];
        const float snt  = hi ? t8a[c] : t8a[c + 4];
        t4a[c] = fmaxf(kept, __shfl_xor(snt, 1));
    }

    float* op = out + (size_t)g * 128 + ((lane & 31) << 2);
    *(float4*)op = make_float4(t4a[0], t4a[1], t4a[2], t4a[3]);
}

extern "C" void kernel_launch(void* const* d_in, const int* in_sizes, int n_in,
                              void* d_out, int out_size, void* d_ws, size_t ws_size,
                              hipStream_t stream) {
    const float* xyz    = (const float*)d_in[0];
    const float* points = (const float*)d_in[1];
    const float* w0 = (const float*)d_in[2];
    const float* b0 = (const float*)d_in[3];
    const float* w1 = (const float*)d_in[4];
    const float* b1 = (const float*)d_in[5];
    const float* w2 = (const float*)d_in[6];
    const float* b2 = (const float*)d_in[7];

    float* out = (float*)d_out;
    float* newxyz = out;                          // (B, S, 3)
    float* newpts = out + (size_t)NB * NS * 3;    // (B, S, 128)
    unsigned short* knn = (unsigned short*)d_ws;  // (B, S, K) u16, 1 MB

    fps_kernel<<<NB, 1024, 0, stream>>>(xyz, newxyz);
    knn_kernel<<<NB * (NS / 16), 1024, 0, stream>>>(xyz, newxyz, knn);
    mlp_kernel<<<(NB * NS) / 8, 256, 0, stream>>>(xyz, points, newxyz, knn,
                                                  w0, b0, w1, b1, w2, b2, newpts);
}

// Round 5
// 1131.353 us; speedup vs baseline: 1.6157x; 1.6157x over previous
//
#include <hip/hip_runtime.h>

#define NB 16
#define NPTS 4096
#define NC 64
#define NS 1024
#define NK 32

// ---------------------------------------------------------------------------
// FPS: one block per batch, 256 threads (4 waves), 16 points/lane in regs.
// Argmax via u64 key (dist_bits<<32 | ~idx): DPP row_ror all-reduce within
// rows of 16, readlane across rows, LDS across waves. Distance arithmetic
// bit-identical to the R4-verified form.
// ---------------------------------------------------------------------------
#define DPP_ROR(x, N) __builtin_amdgcn_update_dpp(0, (int)(x), 0x120 + (N), 0xf, 0xf, false)

__global__ __launch_bounds__(256) void fps_kernel(const float* __restrict__ xyz,
                                                  float* __restrict__ out_xyz) {
    __shared__ float4 pts4[NPTS];
    __shared__ __align__(16) unsigned long long wkey[2][4];

    const int b = blockIdx.x;
    const int t = threadIdx.x;
    const int wv = t >> 6;

    const float* xb = xyz + (size_t)b * NPTS * 3;
    for (int i = t; i < NPTS; i += 256) {
        pts4[i] = make_float4(xb[3 * i], xb[3 * i + 1], xb[3 * i + 2], 0.0f);
    }
    __syncthreads();

    float px[16], py[16], pz[16], dm[16];
#pragma unroll
    for (int j = 0; j < 16; ++j) {
        const float4 p = pts4[t + j * 256];
        px[j] = p.x; py[j] = p.y; pz[j] = p.z;
        dm[j] = 1e10f;
    }

    const float4 c0 = pts4[0];
    float cx = c0.x, cy = c0.y, cz = c0.z;
    float* ob = out_xyz + (size_t)b * NS * 3;

    for (int s = 0; s < NS; ++s) {
        if (t == 0) { ob[3 * s] = cx; ob[3 * s + 1] = cy; ob[3 * s + 2] = cz; }

        // update min-dists and track local argmax (first/lowest index on ties)
        float bv = -1.0f;
        int bg = 0;
#pragma unroll
        for (int j = 0; j < 16; ++j) {
            const float dx = __fsub_rn(px[j], cx);
            const float dy = __fsub_rn(py[j], cy);
            const float dz = __fsub_rn(pz[j], cz);
            const float d = __fadd_rn(__fadd_rn(__fmul_rn(dx, dx), __fmul_rn(dy, dy)),
                                      __fmul_rn(dz, dz));
            dm[j] = fminf(dm[j], d);
            if (dm[j] > bv) { bv = dm[j]; bg = t + j * 256; }
        }

        // pack (dist, idx) into u64 key: max key == max dist, ties -> lowest idx
        unsigned kl = 0xFFFFFFFFu - (unsigned)bg;
        unsigned kh = __float_as_uint(bv);

        // 16-lane all-reduce max via DPP row_ror 1,2,4,8 (VALU-class)
#pragma unroll
        for (int st = 1; st < 16; st <<= 1) {
            unsigned nl, nh;
            if (st == 1)      { nl = (unsigned)DPP_ROR(kl, 1); nh = (unsigned)DPP_ROR(kh, 1); }
            else if (st == 2) { nl = (unsigned)DPP_ROR(kl, 2); nh = (unsigned)DPP_ROR(kh, 2); }
            else if (st == 4) { nl = (unsigned)DPP_ROR(kl, 4); nh = (unsigned)DPP_ROR(kh, 4); }
            else              { nl = (unsigned)DPP_ROR(kl, 8); nh = (unsigned)DPP_ROR(kh, 8); }
            if (nh > kh || (nh == kh && nl > kl)) { kh = nh; kl = nl; }
        }

        // cross-row (4 rows of 16) via readlane; result wave-uniform
        const unsigned a0l = (unsigned)__builtin_amdgcn_readlane((int)kl, 0);
        const unsigned a0h = (unsigned)__builtin_amdgcn_readlane((int)kh, 0);
        const unsigned a1l = (unsigned)__builtin_amdgcn_readlane((int)kl, 16);
        const unsigned a1h = (unsigned)__builtin_amdgcn_readlane((int)kh, 16);
        const unsigned a2l = (unsigned)__builtin_amdgcn_readlane((int)kl, 32);
        const unsigned a2h = (unsigned)__builtin_amdgcn_readlane((int)kh, 32);
        const unsigned a3l = (unsigned)__builtin_amdgcn_readlane((int)kl, 48);
        const unsigned a3h = (unsigned)__builtin_amdgcn_readlane((int)kh, 48);
        const unsigned long long k0 = ((unsigned long long)a0h << 32) | a0l;
        const unsigned long long k1 = ((unsigned long long)a1h << 32) | a1l;
        const unsigned long long k2 = ((unsigned long long)a2h << 32) | a2l;
        const unsigned long long k3 = ((unsigned long long)a3h << 32) | a3l;
        const unsigned long long ka = k0 > k1 ? k0 : k1;
        const unsigned long long kb = k2 > k3 ? k2 : k3;
        const unsigned long long kw = ka > kb ? ka : kb;

        // cross-wave via double-buffered LDS (one barrier per iteration)
        if ((t & 63) == 0) wkey[s & 1][wv] = kw;
        __syncthreads();
        const unsigned long long g0 = wkey[s & 1][0];
        const unsigned long long g1 = wkey[s & 1][1];
        const unsigned long long g2 = wkey[s & 1][2];
        const unsigned long long g3 = wkey[s & 1][3];
        const unsigned long long ha = g0 > g1 ? g0 : g1;
        const unsigned long long hb = g2 > g3 ? g2 : g3;
        const unsigned long long gk = ha > hb ? ha : hb;

        const int wi = (int)(0xFFFFFFFFu - (unsigned)(gk & 0xFFFFFFFFull));
        const float4 c = pts4[wi];
        cx = c.x; cy = c.y; cz = c.z;
    }
}

// ---------------------------------------------------------------------------
// KNN: one wave per query. fp32 expanded-form distances replicating the
// reference's rounding: dot as an FMA chain (numpy SIMD / BLAS style),
// d = (qsq - 2*dot) + psq, qsq/psq sequential no-FMA.  [R4-verified exact]
// Per-lane sorted top-4 + lazy refill; 32 rounds of wave argmin.
// ---------------------------------------------------------------------------
#define KNN_INF 3.0e38f

__global__ __launch_bounds__(1024) void knn_kernel(const float* __restrict__ xyz,
                                                   const float* __restrict__ newxyz,
                                                   unsigned short* __restrict__ knn) {
    __shared__ float4 pts[NPTS];

    const int b = blockIdx.x >> 6;
    const int t = threadIdx.x;
    const float* xb = xyz + (size_t)b * NPTS * 3;
    for (int i = t; i < NPTS; i += 1024) {
        const float x = xb[3 * i], y = xb[3 * i + 1], z = xb[3 * i + 2];
        const float ps = __fadd_rn(__fadd_rn(__fmul_rn(x, x), __fmul_rn(y, y)), __fmul_rn(z, z));
        pts[i] = make_float4(x, y, z, ps);
    }
    __syncthreads();

    const int lane = t & 63;
    const int wv = t >> 6;
    const int s = ((blockIdx.x & 63) << 4) + wv;

    const float* q = newxyz + ((size_t)b * NS + s) * 3;
    const float qx = q[0], qy = q[1], qz = q[2];
    const float qs = __fadd_rn(__fadd_rn(__fmul_rn(qx, qx), __fmul_rn(qy, qy)), __fmul_rn(qz, qz));

    float v0 = KNN_INF, v1 = KNN_INF, v2 = KNN_INF, v3 = KNN_INF;
    int i0 = 0, i1 = 0, i2 = 0, i3 = 0;
    unsigned long long rem = 0ull;

#pragma unroll 4
    for (int j = 0; j < 64; ++j) {
        const float4 p = pts[j * 64 + lane];
        const float dot = __fmaf_rn(qz, p.z, __fmaf_rn(qy, p.y, __fmul_rn(qx, p.x)));
        const float d = __fadd_rn(__fsub_rn(qs, __fadd_rn(dot, dot)), p.w);
        const int gi = j * 64 + lane;
        const bool c0 = d < v0, c1 = d < v1, c2 = d < v2, c3 = d < v3;
        v3 = c3 ? (c2 ? v2 : d) : v3;  i3 = c3 ? (c2 ? i2 : gi) : i3;
        v2 = c2 ? (c1 ? v1 : d) : v2;  i2 = c2 ? (c1 ? i1 : gi) : i2;
        v1 = c1 ? (c0 ? v0 : d) : v1;  i1 = c1 ? (c0 ? i0 : gi) : i1;
        v0 = c0 ? d : v0;              i0 = c0 ? gi : i0;
    }

    int kidx = 0;
#pragma unroll 1
    for (int r = 0; r < NK; ++r) {
        float bv = v0;
        int bi = i0;
#pragma unroll
        for (int m = 1; m < 64; m <<= 1) {
            const float ov = __shfl_xor(bv, m);
            const int   oi = __shfl_xor(bi, m);
            if (ov < bv || (ov == bv && oi < bi)) { bv = ov; bi = oi; }
        }
        if (lane == r) kidx = bi;
        if ((bi & 63) == lane) {
            // pop my head
            v0 = v1; i0 = i1;
            v1 = v2; i1 = i2;
            v2 = v3; i2 = i3;
            v3 = KNN_INF;
            rem |= 1ull << (bi >> 6);
            if (v0 >= 1e37f) {
                // refill from LDS, excluding already-popped slots
                v0 = v1 = v2 = v3 = KNN_INF;
#pragma unroll 1
                for (int j = 0; j < 64; ++j) {
                    if (!((rem >> j) & 1ull)) {
                        const float4 p = pts[j * 64 + lane];
                        const float dot = __fmaf_rn(qz, p.z, __fmaf_rn(qy, p.y, __fmul_rn(qx, p.x)));
                        const float d = __fadd_rn(__fsub_rn(qs, __fadd_rn(dot, dot)), p.w);
                        const int gi = j * 64 + lane;
                        const bool c0 = d < v0, c1 = d < v1, c2 = d < v2, c3 = d < v3;
                        v3 = c3 ? (c2 ? v2 : d) : v3;  i3 = c3 ? (c2 ? i2 : gi) : i3;
                        v2 = c2 ? (c1 ? v1 : d) : v2;  i2 = c2 ? (c1 ? i1 : gi) : i2;
                        v1 = c1 ? (c0 ? v0 : d) : v1;  i1 = c1 ? (c0 ? i0 : gi) : i1;
                        v0 = c0 ? d : v0;              i0 = c0 ? gi : i0;
                    }
                }
            }
        }
    }

    if (lane < NK) knn[(((size_t)b * NS + s) << 5) + lane] = (unsigned short)kidx;
}

// ---------------------------------------------------------------------------
// Gather + 3-layer 1x1-conv MLP + max-pool over K.
// One lane per (group, neighbor) row; 2 groups per wave; 8 groups per block.
// ---------------------------------------------------------------------------
__global__ __launch_bounds__(256) void mlp_kernel(const float* __restrict__ xyz,
                                                  const float* __restrict__ points,
                                                  const float* __restrict__ newxyz,
                                                  const unsigned short* __restrict__ knn,
                                                  const float* __restrict__ w0, const float* __restrict__ b0,
                                                  const float* __restrict__ w1, const float* __restrict__ b1,
                                                  const float* __restrict__ w2, const float* __restrict__ b2,
                                                  float* __restrict__ out) {
    __shared__ float act[67][256];

    const int t = threadIdx.x;
    const int lane = t & 63;
    const int g = blockIdx.x * 8 + ((t >> 6) << 1) + ((lane >> 5) & 1);
    const int b = g >> 10;
    const int k = lane & 31;

    const int idx = knn[((size_t)g << 5) + k];
    const float* nq = newxyz + (size_t)g * 3;
    const float* pp = xyz + ((size_t)b * NPTS + idx) * 3;
    act[0][t] = pp[0] - nq[0];
    act[1][t] = pp[1] - nq[1];
    act[2][t] = pp[2] - nq[2];
    const float4* pr = (const float4*)(points + (((size_t)b * NPTS + idx) << 6));
#pragma unroll
    for (int j = 0; j < 16; ++j) {
        const float4 v = pr[j];
        act[3 + 4 * j][t] = v.x;
        act[4 + 4 * j][t] = v.y;
        act[5 + 4 * j][t] = v.z;
        act[6 + 4 * j][t] = v.w;
    }

    float h[128];

    // layer 1: 67 -> 64
#pragma unroll
    for (int f = 0; f < 64; ++f) h[f] = b0[f];
#pragma unroll 1
    for (int i = 0; i < 67; ++i) {
        const float xi = act[i][t];
        const float* wr = w0 + (i << 6);
#pragma unroll
        for (int f = 0; f < 64; ++f) h[f] = fmaf(xi, wr[f], h[f]);
    }
#pragma unroll
    for (int f = 0; f < 64; ++f) act[f][t] = fmaxf(h[f], 0.0f);

    // layer 2: 64 -> 64
#pragma unroll
    for (int f = 0; f < 64; ++f) h[f] = b1[f];
#pragma unroll 1
    for (int i = 0; i < 64; ++i) {
        const float xi = act[i][t];
        const float* wr = w1 + (i << 6);
#pragma unroll
        for (int f = 0; f < 64; ++f) h[f] = fmaf(xi, wr[f], h[f]);
    }
#pragma unroll
    for (int f = 0; f < 64; ++f) act[f][t] = fmaxf(h[f], 0.0f);

    // layer 3: 64 -> 128
#pragma unroll
    for (int f = 0; f < 128; ++f) h[f] = b2[f];
#pragma unroll 1
    for (int i = 0; i < 64; ++i) {
        const float xi = act[i][t];
        const float* wr = w2 + (i << 7);
#pragma unroll
        for (int f = 0; f < 128; ++f) h[f] = fmaf(xi, wr[f], h[f]);
    }
#pragma unroll
    for (int f = 0; f < 128; ++f) h[f] = fmaxf(h[f], 0.0f);

    // butterfly reduce-scatter max over the 32 lanes of each half-wave.
    // final: lane owns channels 4*(lane&31) + e.
    float t64[64];
#pragma unroll
    for (int c = 0; c < 64; ++c) {
        const bool hi = (lane & 16);
        const float kept = hi ? h[c + 64] : h[c];
        const float snt  = hi ? h[c] : h[c + 64];
        t64[c] = fmaxf(kept, __shfl_xor(snt, 16));
    }
    float t32a[32];
#pragma unroll
    for (int c = 0; c < 32; ++c) {
        const bool hi = (lane & 8);
        const float kept = hi ? t64[c + 32] : t64[c];
        const float snt  = hi ? t64[c] : t64[c + 32];
        t32a[c] = fmaxf(kept, __shfl_xor(snt, 8));
    }
    float t16a[16];
#pragma unroll
    for (int c = 0; c < 16; ++c) {
        const bool hi = (lane & 4);
        const float kept = hi ? t32a[c + 16] : t32a[c];
        const float snt  = hi ? t32a[c] : t32a[c + 16];
        t16a[c] = fmaxf(kept, __shfl_xor(snt, 4));
    }
    float t8a[8];
#pragma unroll
    for (int c = 0; c < 8; ++c) {
        const bool hi = (lane & 2);
        const float kept = hi ? t16a[c + 8] : t16a[c];
        const float snt  = hi ? t16a[c] : t16a[c + 8];
        t8a[c] = fmaxf(kept, __shfl_xor(snt, 2));
    }
    float t4a[4];
#pragma unroll
    for (int c = 0; c < 4; ++c) {
        const bool hi = (lane & 1);
        const float kept = hi ? t8a[c + 4] : t8a[c];
        const float snt  = hi ? t8a[c] : t8a[c + 4];
        t4a[c] = fmaxf(kept, __shfl_xor(snt, 1));
    }

    float* op = out + (size_t)g * 128 + ((lane & 31) << 2);
    *(float4*)op = make_float4(t4a[0], t4a[1], t4a[2], t4a[3]);
}

extern "C" void kernel_launch(void* const* d_in, const int* in_sizes, int n_in,
                              void* d_out, int out_size, void* d_ws, size_t ws_size,
                              hipStream_t stream) {
    const float* xyz    = (const float*)d_in[0];
    const float* points = (const float*)d_in[1];
    const float* w0 = (const float*)d_in[2];
    const float* b0 = (const float*)d_in[3];
    const float* w1 = (const float*)d_in[4];
    const float* b1 = (const float*)d_in[5];
    const float* w2 = (const float*)d_in[6];
    const float* b2 = (const float*)d_in[7];

    float* out = (float*)d_out;
    float* newxyz = out;                          // (B, S, 3)
    float* newpts = out + (size_t)NB * NS * 3;    // (B, S, 128)
    unsigned short* knn = (unsigned short*)d_ws;  // (B, S, K) u16, 1 MB

    fps_kernel<<<NB, 256, 0, stream>>>(xyz, newxyz);
    knn_kernel<<<NB * (NS / 16), 1024, 0, stream>>>(xyz, newxyz, knn);
    mlp_kernel<<<(NB * NS) / 8, 256, 0, stream>>>(xyz, points, newxyz, knn,
                                                  w0, b0, w1, b1, w2, b2, newpts);
}

// Round 6
// 1016.718 us; speedup vs baseline: 1.7979x; 1.1128x over previous
//
#include <hip/hip_runtime.h>

#define NB 16
#define NPTS 4096
#define NC 64
#define NS 1024
#define NK 32

// ---------------------------------------------------------------------------
// FPS: one block per batch, 256 threads (4 waves), 16 points/lane in regs.
// Selection semantics identical to R5 (verified): max dist, lowest index on
// ties, distance arithmetic bit-identical. Structural changes: centroid
// history in LDS (no global store before barrier -> no vmcnt drain), tree
// argmax (depth 4), two-pass f32-max / u32-min DPP wave reduce.
// ---------------------------------------------------------------------------
#define DPP_ROR_I(x, N) __builtin_amdgcn_update_dpp(0, (int)(x), 0x120 + (N), 0xf, 0xf, false)

__global__ __launch_bounds__(256) void fps_kernel(const float* __restrict__ xyz,
                                                  float* __restrict__ out_xyz) {
    __shared__ float4 pts4[NPTS];
    __shared__ float hx[NS], hy[NS], hz[NS];
    __shared__ unsigned wk[2][4][2];  // [buf][wave][kh,kl]

    const int b = blockIdx.x;
    const int t = threadIdx.x;
    const int wv = t >> 6;
    const int lane = t & 63;

    const float* xb = xyz + (size_t)b * NPTS * 3;
    for (int i = t; i < NPTS; i += 256) {
        pts4[i] = make_float4(xb[3 * i], xb[3 * i + 1], xb[3 * i + 2], 0.0f);
    }
    __syncthreads();

    float px[16], py[16], pz[16], dm[16];
#pragma unroll
    for (int j = 0; j < 16; ++j) {
        const float4 p = pts4[t + j * 256];
        px[j] = p.x; py[j] = p.y; pz[j] = p.z;
        dm[j] = 1e10f;
    }

    const float4 c0 = pts4[0];
    float cx = c0.x, cy = c0.y, cz = c0.z;

    for (int s = 0; s < NS; ++s) {
        if (t == 0) { hx[s] = cx; hy[s] = cy; hz[s] = cz; }

        // update min-dists (independent across j; bit-identical arithmetic)
#pragma unroll
        for (int j = 0; j < 16; ++j) {
            const float dx = __fsub_rn(px[j], cx);
            const float dy = __fsub_rn(py[j], cy);
            const float dz = __fsub_rn(pz[j], cz);
            const float d = __fadd_rn(__fadd_rn(__fmul_rn(dx, dx), __fmul_rn(dy, dy)),
                                      __fmul_rn(dz, dz));
            dm[j] = fminf(dm[j], d);
        }

        // lane max via depth-4 fmax tree
        float a8[8], a4[4], a2[2];
#pragma unroll
        for (int j = 0; j < 8; ++j) a8[j] = fmaxf(dm[2 * j], dm[2 * j + 1]);
#pragma unroll
        for (int j = 0; j < 4; ++j) a4[j] = fmaxf(a8[2 * j], a8[2 * j + 1]);
        a2[0] = fmaxf(a4[0], a4[1]);
        a2[1] = fmaxf(a4[2], a4[3]);
        const float mv = fmaxf(a2[0], a2[1]);

        // lane arg (lowest global idx among ties) via depth-4 min-u32 tree
        unsigned u16a[16], u8[8], u4[4], u2[2];
#pragma unroll
        for (int j = 0; j < 16; ++j)
            u16a[j] = (dm[j] == mv) ? (unsigned)(t + j * 256) : 0xFFFFFFFFu;
#pragma unroll
        for (int j = 0; j < 8; ++j) u8[j] = u16a[2 * j] < u16a[2 * j + 1] ? u16a[2 * j] : u16a[2 * j + 1];
#pragma unroll
        for (int j = 0; j < 4; ++j) u4[j] = u8[2 * j] < u8[2 * j + 1] ? u8[2 * j] : u8[2 * j + 1];
        u2[0] = u4[0] < u4[1] ? u4[0] : u4[1];
        u2[1] = u4[2] < u4[3] ? u4[2] : u4[3];
        const unsigned best = u2[0] < u2[1] ? u2[0] : u2[1];

        // wave max: 4x DPP row_ror f32-max (row all-reduce), readlane across rows
        float r = mv;
        { const float o = __int_as_float(DPP_ROR_I(__float_as_int(r), 1)); r = fmaxf(r, o); }
        { const float o = __int_as_float(DPP_ROR_I(__float_as_int(r), 2)); r = fmaxf(r, o); }
        { const float o = __int_as_float(DPP_ROR_I(__float_as_int(r), 4)); r = fmaxf(r, o); }
        { const float o = __int_as_float(DPP_ROR_I(__float_as_int(r), 8)); r = fmaxf(r, o); }
        const float q0 = __int_as_float(__builtin_amdgcn_readlane(__float_as_int(r), 0));
        const float q1 = __int_as_float(__builtin_amdgcn_readlane(__float_as_int(r), 16));
        const float q2 = __int_as_float(__builtin_amdgcn_readlane(__float_as_int(r), 32));
        const float q3 = __int_as_float(__builtin_amdgcn_readlane(__float_as_int(r), 48));
        const float wm = fmaxf(fmaxf(q0, q1), fmaxf(q2, q3));

        // wave arg: candidates where lane max == wave max, min-u32 all-reduce
        unsigned c = (mv == wm) ? best : 0xFFFFFFFFu;
        { const unsigned o = (unsigned)DPP_ROR_I(c, 1); c = o < c ? o : c; }
        { const unsigned o = (unsigned)DPP_ROR_I(c, 2); c = o < c ? o : c; }
        { const unsigned o = (unsigned)DPP_ROR_I(c, 4); c = o < c ? o : c; }
        { const unsigned o = (unsigned)DPP_ROR_I(c, 8); c = o < c ? o : c; }
        const unsigned g0 = (unsigned)__builtin_amdgcn_readlane((int)c, 0);
        const unsigned g1 = (unsigned)__builtin_amdgcn_readlane((int)c, 16);
        const unsigned g2 = (unsigned)__builtin_amdgcn_readlane((int)c, 32);
        const unsigned g3 = (unsigned)__builtin_amdgcn_readlane((int)c, 48);
        const unsigned ga = g0 < g1 ? g0 : g1;
        const unsigned gb = g2 < g3 ? g2 : g3;
        const unsigned wgi = ga < gb ? ga : gb;

        // cross-wave merge via double-buffered LDS keys (one barrier/iter)
        if (lane == 0) { wk[s & 1][wv][0] = __float_as_uint(wm); wk[s & 1][wv][1] = ~wgi; }
        __syncthreads();
        const unsigned long long k0 = ((unsigned long long)wk[s & 1][0][0] << 32) | wk[s & 1][0][1];
        const unsigned long long k1 = ((unsigned long long)wk[s & 1][1][0] << 32) | wk[s & 1][1][1];
        const unsigned long long k2 = ((unsigned long long)wk[s & 1][2][0] << 32) | wk[s & 1][2][1];
        const unsigned long long k3 = ((unsigned long long)wk[s & 1][3][0] << 32) | wk[s & 1][3][1];
        const unsigned long long ka = k0 > k1 ? k0 : k1;
        const unsigned long long kb = k2 > k3 ? k2 : k3;
        const unsigned long long kw = ka > kb ? ka : kb;

        const int wi = (int)(~(unsigned)kw);
        const float4 cc = pts4[wi];
        cx = cc.x; cy = cc.y; cz = cc.z;
    }

    // flush centroid history to global, coalesced
    __syncthreads();
    float* ob = out_xyz + (size_t)b * NS * 3;
#pragma unroll
    for (int r2 = 0; r2 < 12; ++r2) {
        const int f = t + r2 * 256;
        const int i = f / 3;
        const int cmp = f - 3 * i;
        const float v = (cmp == 0) ? hx[i] : ((cmp == 1) ? hy[i] : hz[i]);
        ob[f] = v;
    }
}

// ---------------------------------------------------------------------------
// KNN: one wave per query. fp32 expanded-form distances replicating the
// reference's rounding: dot as an FMA chain, d = (qsq - 2*dot) + psq,
// qsq/psq sequential no-FMA.  [R4-verified exact]
// Per-lane sorted top-4 + lazy refill; 32 rounds of wave argmin.
// ---------------------------------------------------------------------------
#define KNN_INF 3.0e38f

__global__ __launch_bounds__(1024) void knn_kernel(const float* __restrict__ xyz,
                                                   const float* __restrict__ newxyz,
                                                   unsigned short* __restrict__ knn) {
    __shared__ float4 pts[NPTS];

    const int b = blockIdx.x >> 6;
    const int t = threadIdx.x;
    const float* xb = xyz + (size_t)b * NPTS * 3;
    for (int i = t; i < NPTS; i += 1024) {
        const float x = xb[3 * i], y = xb[3 * i + 1], z = xb[3 * i + 2];
        const float ps = __fadd_rn(__fadd_rn(__fmul_rn(x, x), __fmul_rn(y, y)), __fmul_rn(z, z));
        pts[i] = make_float4(x, y, z, ps);
    }
    __syncthreads();

    const int lane = t & 63;
    const int wv = t >> 6;
    const int s = ((blockIdx.x & 63) << 4) + wv;

    const float* q = newxyz + ((size_t)b * NS + s) * 3;
    const float qx = q[0], qy = q[1], qz = q[2];
    const float qs = __fadd_rn(__fadd_rn(__fmul_rn(qx, qx), __fmul_rn(qy, qy)), __fmul_rn(qz, qz));

    float v0 = KNN_INF, v1 = KNN_INF, v2 = KNN_INF, v3 = KNN_INF;
    int i0 = 0, i1 = 0, i2 = 0, i3 = 0;
    unsigned long long rem = 0ull;

#pragma unroll 4
    for (int j = 0; j < 64; ++j) {
        const float4 p = pts[j * 64 + lane];
        const float dot = __fmaf_rn(qz, p.z, __fmaf_rn(qy, p.y, __fmul_rn(qx, p.x)));
        const float d = __fadd_rn(__fsub_rn(qs, __fadd_rn(dot, dot)), p.w);
        const int gi = j * 64 + lane;
        const bool c0 = d < v0, c1 = d < v1, c2 = d < v2, c3 = d < v3;
        v3 = c3 ? (c2 ? v2 : d) : v3;  i3 = c3 ? (c2 ? i2 : gi) : i3;
        v2 = c2 ? (c1 ? v1 : d) : v2;  i2 = c2 ? (c1 ? i1 : gi) : i2;
        v1 = c1 ? (c0 ? v0 : d) : v1;  i1 = c1 ? (c0 ? i0 : gi) : i1;
        v0 = c0 ? d : v0;              i0 = c0 ? gi : i0;
    }

    int kidx = 0;
#pragma unroll 1
    for (int r = 0; r < NK; ++r) {
        float bv = v0;
        int bi = i0;
#pragma unroll
        for (int m = 1; m < 64; m <<= 1) {
            const float ov = __shfl_xor(bv, m);
            const int   oi = __shfl_xor(bi, m);
            if (ov < bv || (ov == bv && oi < bi)) { bv = ov; bi = oi; }
        }
        if (lane == r) kidx = bi;
        if ((bi & 63) == lane) {
            v0 = v1; i0 = i1;
            v1 = v2; i1 = i2;
            v2 = v3; i2 = i3;
            v3 = KNN_INF;
            rem |= 1ull << (bi >> 6);
            if (v0 >= 1e37f) {
                v0 = v1 = v2 = v3 = KNN_INF;
#pragma unroll 1
                for (int j = 0; j < 64; ++j) {
                    if (!((rem >> j) & 1ull)) {
                        const float4 p = pts[j * 64 + lane];
                        const float dot = __fmaf_rn(qz, p.z, __fmaf_rn(qy, p.y, __fmul_rn(qx, p.x)));
                        const float d = __fadd_rn(__fsub_rn(qs, __fadd_rn(dot, dot)), p.w);
                        const int gi = j * 64 + lane;
                        const bool c0 = d < v0, c1 = d < v1, c2 = d < v2, c3 = d < v3;
                        v3 = c3 ? (c2 ? v2 : d) : v3;  i3 = c3 ? (c2 ? i2 : gi) : i3;
                        v2 = c2 ? (c1 ? v1 : d) : v2;  i2 = c2 ? (c1 ? i1 : gi) : i2;
                        v1 = c1 ? (c0 ? v0 : d) : v1;  i1 = c1 ? (c0 ? i0 : gi) : i1;
                        v0 = c0 ? d : v0;              i0 = c0 ? gi : i0;
                    }
                }
            }
        }
    }

    if (lane < NK) knn[(((size_t)b * NS + s) << 5) + lane] = (unsigned short)kidx;
}

// ---------------------------------------------------------------------------
// Gather + 3-layer 1x1-conv MLP + max-pool over K.
// One lane per (group, neighbor) row; 2 groups per wave; 8 groups per block.
// ---------------------------------------------------------------------------
__global__ __launch_bounds__(256) void mlp_kernel(const float* __restrict__ xyz,
                                                  const float* __restrict__ points,
                                                  const float* __restrict__ newxyz,
                                                  const unsigned short* __restrict__ knn,
                                                  const float* __restrict__ w0, const float* __restrict__ b0,
                                                  const float* __restrict__ w1, const float* __restrict__ b1,
                                                  const float* __restrict__ w2, const float* __restrict__ b2,
                                                  float* __restrict__ out) {
    __shared__ float act[67][256];

    const int t = threadIdx.x;
    const int lane = t & 63;
    const int g = blockIdx.x * 8 + ((t >> 6) << 1) + ((lane >> 5) & 1);
    const int b = g >> 10;
    const int k = lane & 31;

    const int idx = knn[((size_t)g << 5) + k];
    const float* nq = newxyz + (size_t)g * 3;
    const float* pp = xyz + ((size_t)b * NPTS + idx) * 3;
    act[0][t] = pp[0] - nq[0];
    act[1][t] = pp[1] - nq[1];
    act[2][t] = pp[2] - nq[2];
    const float4* pr = (const float4*)(points + (((size_t)b * NPTS + idx) << 6));
#pragma unroll
    for (int j = 0; j < 16; ++j) {
        const float4 v = pr[j];
        act[3 + 4 * j][t] = v.x;
        act[4 + 4 * j][t] = v.y;
        act[5 + 4 * j][t] = v.z;
        act[6 + 4 * j][t] = v.w;
    }

    float h[128];

    // layer 1: 67 -> 64
#pragma unroll
    for (int f = 0; f < 64; ++f) h[f] = b0[f];
#pragma unroll 1
    for (int i = 0; i < 67; ++i) {
        const float xi = act[i][t];
        const float* wr = w0 + (i << 6);
#pragma unroll
        for (int f = 0; f < 64; ++f) h[f] = fmaf(xi, wr[f], h[f]);
    }
#pragma unroll
    for (int f = 0; f < 64; ++f) act[f][t] = fmaxf(h[f], 0.0f);

    // layer 2: 64 -> 64
#pragma unroll
    for (int f = 0; f < 64; ++f) h[f] = b1[f];
#pragma unroll 1
    for (int i = 0; i < 64; ++i) {
        const float xi = act[i][t];
        const float* wr = w1 + (i << 6);
#pragma unroll
        for (int f = 0; f < 64; ++f) h[f] = fmaf(xi, wr[f], h[f]);
    }
#pragma unroll
    for (int f = 0; f < 64; ++f) act[f][t] = fmaxf(h[f], 0.0f);

    // layer 3: 64 -> 128
#pragma unroll
    for (int f = 0; f < 128; ++f) h[f] = b2[f];
#pragma unroll 1
    for (int i = 0; i < 64; ++i) {
        const float xi = act[i][t];
        const float* wr = w2 + (i << 7);
#pragma unroll
        for (int f = 0; f < 128; ++f) h[f] = fmaf(xi, wr[f], h[f]);
    }
#pragma unroll
    for (int f = 0; f < 128; ++f) h[f] = fmaxf(h[f], 0.0f);

    // butterfly reduce-scatter max over the 32 lanes of each half-wave.
    float t64[64];
#pragma unroll
    for (int c = 0; c < 64; ++c) {
        const bool hi = (lane & 16);
        const float kept = hi ? h[c + 64] : h[c];
        const float snt  = hi ? h[c] : h[c + 64];
        t64[c] = fmaxf(kept, __shfl_xor(snt, 16));
    }
    float t32a[32];
#pragma unroll
    for (int c = 0; c < 32; ++c) {
        const bool hi = (lane & 8);
        const float kept = hi ? t64[c + 32] : t64[c];
        const float snt  = hi ? t64[c] : t64[c + 32];
        t32a[c] = fmaxf(kept, __shfl_xor(snt, 8));
    }
    float t16a[16];
#pragma unroll
    for (int c = 0; c < 16; ++c) {
        const bool hi = (lane & 4);
        const float kept = hi ? t32a[c + 16] : t32a[c];
        const float snt  = hi ? t32a[c] : t32a[c + 16];
        t16a[c] = fmaxf(kept, __shfl_xor(snt, 4));
    }
    float t8a[8];
#pragma unroll
    for (int c = 0; c < 8; ++c) {
        const bool hi = (lane & 2);
        const float kept = hi ? t16a[c + 8] : t16a[c];
        const float snt  = hi ? t16a[c] : t16a[c + 8];
        t8a[c] = fmaxf(kept, __shfl_xor(snt, 2));
    }
    float t4a[4];
#pragma unroll
    for (int c = 0; c < 4; ++c) {
        const bool hi = (lane & 1);
        const float kept = hi ? t8a[c + 4] : t8a[c];
        const float snt  = hi ? t8a[c] : t8a[c + 4];
        t4a[c] = fmaxf(kept, __shfl_xor(snt, 1));
    }

    float* op = out + (size_t)g * 128 + ((lane & 31) << 2);
    *(float4*)op = make_float4(t4a[0], t4a[1], t4a[2], t4a[3]);
}

extern "C" void kernel_launch(void* const* d_in, const int* in_sizes, int n_in,
                              void* d_out, int out_size, void* d_ws, size_t ws_size,
                              hipStream_t stream) {
    const float* xyz    = (const float*)d_in[0];
    const float* points = (const float*)d_in[1];
    const float* w0 = (const float*)d_in[2];
    const float* b0 = (const float*)d_in[3];
    const float* w1 = (const float*)d_in[4];
    const float* b1 = (const float*)d_in[5];
    const float* w2 = (const float*)d_in[6];
    const float* b2 = (const float*)d_in[7];

    float* out = (float*)d_out;
    float* newxyz = out;                          // (B, S, 3)
    float* newpts = out + (size_t)NB * NS * 3;    // (B, S, 128)
    unsigned short* knn = (unsigned short*)d_ws;  // (B, S, K) u16, 1 MB

    fps_kernel<<<NB, 256, 0, stream>>>(xyz, newxyz);
    knn_kernel<<<NB * (NS / 16), 1024, 0, stream>>>(xyz, newxyz, knn);
    mlp_kernel<<<(NB * NS) / 8, 256, 0, stream>>>(xyz, points, newxyz, knn,
                                                  w0, b0, w1, b1, w2, b2, newpts);
}